// Round 12
// baseline (401.770 us; speedup 1.0000x reference)
//
#include <hip/hip_runtime.h>
#include <hip/hip_bf16.h>

#define NN 50000
#define NE 800000
#define HID 128
#define NB 32
#define SCAN_B 196   // 196*256 = 50176 >= NN
#define SD_B 782     // sd tiles: ceil(50000/64)

typedef short short8 __attribute__((ext_vector_type(8)));
typedef float f32x4 __attribute__((ext_vector_type(4)));

static __device__ __forceinline__ short f2bf(float x) {
    union { __hip_bfloat16 h; short s; } r;
    r.h = __float2bfloat16(x);       // HW RNE cvt
    return r.s;
}
static __device__ __forceinline__ float bf2f(unsigned short s) {
    return __uint_as_float(((unsigned int)s) << 16);
}
// packed bf16 add (HW packed add on gfx950)
static __device__ __forceinline__ unsigned int addpack(unsigned int a, unsigned int b) {
    union { unsigned int u; __hip_bfloat162 h; } x, y, r;
    x.u = a; y.u = b;
    r.h = __hadd2(x.h, y.h);
    return r.u;
}

// ---- prep: zero out + dst histogram (blocks < 3125) + weight transposes ----
__global__ void fused_prep(const int* __restrict__ dstI, int* __restrict__ counts,
                           const float* __restrict__ W1, const float* __restrict__ W2,
                           const float* __restrict__ Wo,
                           short* __restrict__ W1aT, short* __restrict__ W1bT,
                           short* __restrict__ W1cT, short* __restrict__ W2t,
                           short* __restrict__ Wot,
                           float* __restrict__ out) {
    int b = blockIdx.x;
    // grid-stride zero of out (all blocks participate; overlaps histogram)
    {
        int gtid = b * 256 + threadIdx.x;
        const int nthr = 3397 * 256;
        float4 z = make_float4(0.f, 0.f, 0.f, 0.f);
        for (int i = gtid; i < NN * HID / 4; i += nthr)
            ((float4*)out)[i] = z;
    }
    if (b < 3125) {
        int e = b * 256 + threadIdx.x;
        atomicAdd(&counts[dstI[e]], 1);
    } else {
        int t = (b - 3125) * 256 + threadIdx.x;   // 0..69631
        if (t < 16384) {
            int n = t >> 7, k = t & 127;
            W1aT[t] = f2bf(W1[k * HID + n]);
        } else if ((t -= 16384) < 16384) {
            int n = t >> 7, k = t & 127;
            W1bT[t] = f2bf(W1[(k + 128) * HID + n]);
        } else if ((t -= 16384) < 4096) {
            int n = t >> 5, k = t & 31;
            W1cT[t] = f2bf(W1[(k + 256) * HID + n]);
        } else if ((t -= 4096) < 16384) {
            int n = t >> 7, k = t & 127;
            W2t[t] = f2bf(W2[k * HID + n]);
        } else if ((t -= 16384) < 16384) {
            int n = t >> 7, k = t & 127;
            Wot[t] = f2bf(Wo[k * HID + n]);
        }
    }
}

// ---- scan stage 1 ----
__global__ void k_scan1(const int* __restrict__ counts, int* __restrict__ scanEx,
                        int* __restrict__ blockSum) {
    __shared__ int s[256];
    int t = threadIdx.x, idx = blockIdx.x * 256 + t;
    int v = counts[idx];   // counts sized 50176, zeroed
    s[t] = v; __syncthreads();
    #pragma unroll
    for (int off = 1; off < 256; off <<= 1) {
        int x = (t >= off) ? s[t - off] : 0;
        __syncthreads();
        s[t] += x;
        __syncthreads();
    }
    scanEx[idx] = s[t] - v;
    if (t == 255) blockSum[blockIdx.x] = s[255];
}

// ---- scan stage 2+3 fused: cur = scanEx + sum(blockSum[0..b)) ----
__global__ void k_scan23(const int* __restrict__ scanEx, const int* __restrict__ blockSum,
                         int* __restrict__ cur) {
    __shared__ int s[256];
    int t = threadIdx.x, b = blockIdx.x;
    s[t] = (t < b) ? blockSum[t] : 0;
    __syncthreads();
    #pragma unroll
    for (int off = 128; off > 0; off >>= 1) {
        if (t < off) s[t] += s[t + off];
        __syncthreads();
    }
    int idx = b * 256 + t;
    cur[idx] = scanEx[idx] + s[0];
}

// ---- fused: sd GEMM (blocks < SD_B) + edge permute (blocks >= SD_B) ----
__launch_bounds__(256, 4)
__global__ void perm_sd(const float* __restrict__ nf,
                        const short* __restrict__ W1aT, const short* __restrict__ W1bT,
                        short* __restrict__ Sg, short* __restrict__ Dg,
                        const int* __restrict__ src, const int* __restrict__ dst,
                        int* __restrict__ cur, int2* __restrict__ edgeS) {
    __shared__ short As[64 * 136];
    const int tid = threadIdx.x;

    if (blockIdx.x >= SD_B) {
        // ---- permute role ----
        int e = (blockIdx.x - SD_B) * 256 + tid;
        int s = src[e];
        int d = dst[e];
        int r = atomicAdd(&cur[d], 1);
        edgeS[r] = make_int2(s, d);
        return;
    }

    // ---- sd role: S = nf@W1a, D = nf@W1b (bf16 out, coalesced via LDS repack) ----
    const int wave = tid >> 6;
    const int lane = tid & 63;
    const int quad = lane >> 4;
    const int l15  = lane & 15;
    const int n0   = blockIdx.x * 64;
    const int row  = tid >> 2, pt = tid & 3;

    {
        int node = min(n0 + row, NN - 1);
        const float4* p = (const float4*)(nf + (size_t)node * HID + pt * 32);
        #pragma unroll
        for (int j = 0; j < 4; ++j) {
            float4 w0 = p[j * 2], w1 = p[j * 2 + 1];
            short8 o;
            o[0] = f2bf(w0.x); o[1] = f2bf(w0.y); o[2] = f2bf(w0.z); o[3] = f2bf(w0.w);
            o[4] = f2bf(w1.x); o[5] = f2bf(w1.y); o[6] = f2bf(w1.z); o[7] = f2bf(w1.w);
            *(short8*)(As + row * 136 + pt * 32 + j * 8) = o;
        }
    }
    __syncthreads();

    f32x4 aS[4][2], aD[4][2];
    #pragma unroll
    for (int mt = 0; mt < 4; ++mt)
        #pragma unroll
        for (int nt = 0; nt < 2; ++nt) {
            aS[mt][nt] = (f32x4){0.f, 0.f, 0.f, 0.f};
            aD[mt][nt] = (f32x4){0.f, 0.f, 0.f, 0.f};
        }

    #pragma unroll
    for (int kk = 0; kk < 4; ++kk) {
        int ko = kk * 32 + quad * 8;
        short8 a[4];
        #pragma unroll
        for (int mt = 0; mt < 4; ++mt)
            a[mt] = *(const short8*)(As + (mt * 16 + l15) * 136 + ko);
        #pragma unroll
        for (int nt = 0; nt < 2; ++nt) {
            int n = wave * 32 + nt * 16 + l15;
            short8 bS = *(const short8*)(W1aT + n * HID + ko);
            short8 bD = *(const short8*)(W1bT + n * HID + ko);
            #pragma unroll
            for (int mt = 0; mt < 4; ++mt) {
                aS[mt][nt] = __builtin_amdgcn_mfma_f32_16x16x32_bf16(a[mt], bS, aS[mt][nt], 0, 0, 0);
                aD[mt][nt] = __builtin_amdgcn_mfma_f32_16x16x32_bf16(a[mt], bD, aD[mt][nt], 0, 0, 0);
            }
        }
    }
    __syncthreads();   // A-frag reads done; reuse As for repack

    // repack S -> coalesced row stores
    #pragma unroll
    for (int nt = 0; nt < 2; ++nt) {
        int col = wave * 32 + nt * 16 + l15;
        #pragma unroll
        for (int mt = 0; mt < 4; ++mt)
            #pragma unroll
            for (int r = 0; r < 4; ++r)
                As[(mt * 16 + quad * 4 + r) * 136 + col] = f2bf(aS[mt][nt][r]);
    }
    __syncthreads();
    if (n0 + row < NN) {
        short8* gp = (short8*)(Sg + (size_t)(n0 + row) * HID + pt * 32);
        #pragma unroll
        for (int j = 0; j < 4; ++j)
            gp[j] = *(const short8*)(As + row * 136 + pt * 32 + j * 8);
    }
    __syncthreads();

    // repack D -> coalesced row stores
    #pragma unroll
    for (int nt = 0; nt < 2; ++nt) {
        int col = wave * 32 + nt * 16 + l15;
        #pragma unroll
        for (int mt = 0; mt < 4; ++mt)
            #pragma unroll
            for (int r = 0; r < 4; ++r)
                As[(mt * 16 + quad * 4 + r) * 136 + col] = f2bf(aD[mt][nt][r]);
    }
    __syncthreads();
    if (n0 + row < NN) {
        short8* gp = (short8*)(Dg + (size_t)(n0 + row) * HID + pt * 32);
        #pragma unroll
        for (int j = 0; j < 4; ++j)
            gp[j] = *(const short8*)(As + row * 136 + pt * 32 + j * 8);
    }
}

// ---- fused edge MLP + tile-merged scatter (edges sorted by dst) ----
// 128 edges/block, 512 threads. B-fragments prefetched to registers at entry.
__launch_bounds__(512, 6)
__global__ void edge_kernel(const short* __restrict__ Sg,
                            const short* __restrict__ Dg,
                            const float* __restrict__ pos,
                            const int2* __restrict__ edgeS,
                            const short* __restrict__ W1cT,
                            const float* __restrict__ b1,
                            const short* __restrict__ W2t,
                            const float* __restrict__ b2,
                            float* __restrict__ upd) {
    __shared__ char buf[49152];
    __shared__ int  dn_sh[128];
    short* PRE = (short*)buf;              // [128][136] bf16: S[src]+D[dst]
    short* R   = (short*)(buf + 34816);    // [128][56]  bf16 rbf
    short* Ps  = (short*)buf;              // [128][136] (in-place after PRE consumed)
    float* UfT = (float*)buf;              // [128 cols][68] fp32, one 64-row half

    const int tid  = threadIdx.x;
    const int wave = tid >> 6;
    const int lane = tid & 63;
    const int quad = lane >> 4;
    const int l15  = lane & 15;
    const int mg   = wave >> 2;       // row half: [mg*64, mg*64+64)
    const int nsl  = wave & 3;        // col slice: [nsl*32, nsl*32+32)
    const int e0   = blockIdx.x * 128;
    const int ko0  = quad * 8;

    // ---- prefetch all B-fragments into registers (overlaps staging) ----
    short8 w1c_f[2], w2t_f[4][2];
    #pragma unroll
    for (int nt = 0; nt < 2; ++nt) {
        int n = nsl * 32 + nt * 16 + l15;
        w1c_f[nt] = *(const short8*)(W1cT + n * NB + ko0);
        #pragma unroll
        for (int kk = 0; kk < 4; ++kk)
            w2t_f[kk][nt] = *(const short8*)(W2t + n * HID + kk * 32 + ko0);
    }
    float b1c[2] = { b1[nsl * 32 + l15], b1[nsl * 32 + 16 + l15] };
    float b2c[2] = { b2[nsl * 32 + l15], b2[nsl * 32 + 16 + l15] };

    // ---- stage: PRE = S[src]+D[dst] (packed bf16 HW add), RBF tile, dst ids ----
    {
        int es = tid >> 2, pt = tid & 3;
        int2 sd = edgeS[e0 + es];
        int s = sd.x, d = sd.y;
        const int4* sp = (const int4*)(Sg + (size_t)s * HID + pt * 32);
        const int4* dp = (const int4*)(Dg + (size_t)d * HID + pt * 32);
        int4* op = (int4*)(PRE + es * 136 + pt * 32);
        #pragma unroll
        for (int j = 0; j < 4; ++j) {
            int4 a = sp[j], b = dp[j];
            int4 o;
            o.x = addpack(a.x, b.x);
            o.y = addpack(a.y, b.y);
            o.z = addpack(a.z, b.z);
            o.w = addpack(a.w, b.w);
            op[j] = o;
        }
        if (pt == 0) dn_sh[es] = d;
        float dx = pos[d * 3 + 0] - pos[s * 3 + 0];
        float dy = pos[d * 3 + 1] - pos[s * 3 + 1];
        float dz = pos[d * 3 + 2] - pos[s * 3 + 2];
        float dd = fminf(sqrtf(dx * dx + dy * dy + dz * dz), 5.0f);
        const float step  = 5.0f / 31.0f;
        const float width = 0.5f * (step + 0.01f);
        const float coef  = -0.5f / (width * width);
        short8 r;
        #pragma unroll
        for (int j = 0; j < 8; ++j) {
            float c = step * (float)(pt * 8 + j);
            float t = dd - c;
            r[j] = f2bf(__expf(coef * t * t));
        }
        *(short8*)(R + es * 56 + pt * 8) = r;
    }
    __syncthreads();

    // ---- layer 1: rbf [128x32] @ W1c [32x128], single K-step ----
    f32x4 acc[4][2];
    #pragma unroll
    for (int mt = 0; mt < 4; ++mt)
        #pragma unroll
        for (int nt = 0; nt < 2; ++nt) acc[mt][nt] = (f32x4){0.f, 0.f, 0.f, 0.f};
    {
        short8 a[4];
        #pragma unroll
        for (int mt = 0; mt < 4; ++mt)
            a[mt] = *(const short8*)(R + (mg * 64 + mt * 16 + l15) * 56 + ko0);
        #pragma unroll
        for (int nt = 0; nt < 2; ++nt)
            #pragma unroll
            for (int mt = 0; mt < 4; ++mt)
                acc[mt][nt] = __builtin_amdgcn_mfma_f32_16x16x32_bf16(a[mt], w1c_f[nt], acc[mt][nt], 0, 0, 0);
    }

    // ---- + PRE + b1, SiLU -> Ps in place ----
    {
        const unsigned short* PREu = (const unsigned short*)PRE;
        #pragma unroll
        for (int nt = 0; nt < 2; ++nt) {
            int col = nsl * 32 + nt * 16 + l15;
            #pragma unroll
            for (int mt = 0; mt < 4; ++mt) {
                #pragma unroll
                for (int r = 0; r < 4; ++r) {
                    int row = mg * 64 + mt * 16 + quad * 4 + r;
                    float pre = bf2f(PREu[row * 136 + col]);
                    float x = acc[mt][nt][r] + pre + b1c[nt];
                    float p = x * __builtin_amdgcn_rcpf(1.0f + __expf(-x));
                    Ps[row * 136 + col] = f2bf(p);
                }
            }
        }
    }
    __syncthreads();

    // ---- layer 2: [128x128] @ [128x128] ----
    f32x4 acc2[4][2];
    #pragma unroll
    for (int mt = 0; mt < 4; ++mt)
        #pragma unroll
        for (int nt = 0; nt < 2; ++nt) acc2[mt][nt] = (f32x4){0.f, 0.f, 0.f, 0.f};

    #pragma unroll
    for (int kk = 0; kk < 4; ++kk) {
        int ko = kk * 32 + ko0;
        short8 a[4];
        #pragma unroll
        for (int mt = 0; mt < 4; ++mt)
            a[mt] = *(const short8*)(Ps + (mg * 64 + mt * 16 + l15) * 136 + ko);
        #pragma unroll
        for (int nt = 0; nt < 2; ++nt)
            #pragma unroll
            for (int mt = 0; mt < 4; ++mt)
                acc2[mt][nt] = __builtin_amdgcn_mfma_f32_16x16x32_bf16(a[mt], w2t_f[kk][nt], acc2[mt][nt], 0, 0, 0);
    }
    __syncthreads();   // Ps reads done before UfT overwrites

    // ---- two 64-row halves: transposed fp32 buffer + merged scatter ----
    #pragma unroll
    for (int h = 0; h < 2; ++h) {
        if (mg == h) {
            #pragma unroll
            for (int nt = 0; nt < 2; ++nt) {
                int col = nsl * 32 + nt * 16 + l15;
                #pragma unroll
                for (int mt = 0; mt < 4; ++mt) {
                    f32x4 v;
                    #pragma unroll
                    for (int r = 0; r < 4; ++r) v[r] = acc2[mt][nt][r] + b2c[nt];
                    *(f32x4*)(UfT + col * 68 + mt * 16 + quad * 4) = v;
                }
            }
        }
        __syncthreads();
        {
            int col = tid & 127;
            int seg = tid >> 7;            // 4 segments x 16 rows
            int rb  = h * 64 + seg * 16;
            const float* cp = UfT + col * 68 + seg * 16;
            f32x4 vv[4];
            #pragma unroll
            for (int j = 0; j < 4; ++j) vv[j] = *(const f32x4*)(cp + j * 4);
            int rnode = dn_sh[rb];
            float run = 0.0f;
            #pragma unroll
            for (int i = 0; i < 16; ++i) {
                int node = dn_sh[rb + i];
                float v = vv[i >> 2][i & 3];
                if (node != rnode) {
                    atomicAdd(upd + (size_t)rnode * HID + col, run);
                    rnode = node;
                    run = v;
                } else {
                    run += v;
                }
            }
            atomicAdd(upd + (size_t)rnode * HID + col, run);
        }
        __syncthreads();
    }
}

// ---- normalize by degree + @Wo + bo (MFMA), in place on d_out ----
__launch_bounds__(256, 4)
__global__ void out_kernel(float* __restrict__ out,
                           const int* __restrict__ counts,
                           const short* __restrict__ Wot,
                           const float* __restrict__ bo) {
    __shared__ short A2[64 * 136];

    const int tid  = threadIdx.x;
    const int wave = tid >> 6;
    const int lane = tid & 63;
    const int quad = lane >> 4;
    const int l15  = lane & 15;
    const int n0   = blockIdx.x * 64;

    {
        int row = tid >> 2, pt = tid & 3;
        int node = n0 + row;
        if (node < NN) {
            float inv = 1.0f / fmaxf((float)counts[node], 1.0f);
            const float4* p = (const float4*)(out + (size_t)node * HID + pt * 32);
            #pragma unroll
            for (int j = 0; j < 4; ++j) {
                float4 w0 = p[j * 2], w1 = p[j * 2 + 1];
                short8 o;
                o[0] = f2bf(w0.x * inv); o[1] = f2bf(w0.y * inv);
                o[2] = f2bf(w0.z * inv); o[3] = f2bf(w0.w * inv);
                o[4] = f2bf(w1.x * inv); o[5] = f2bf(w1.y * inv);
                o[6] = f2bf(w1.z * inv); o[7] = f2bf(w1.w * inv);
                *(short8*)(A2 + row * 136 + pt * 32 + j * 8) = o;
            }
        } else {
            short8 z = (short8){0, 0, 0, 0, 0, 0, 0, 0};
            #pragma unroll
            for (int j = 0; j < 4; ++j)
                *(short8*)(A2 + row * 136 + pt * 32 + j * 8) = z;
        }
    }
    __syncthreads();

    f32x4 acc[4][2];
    #pragma unroll
    for (int mt = 0; mt < 4; ++mt)
        #pragma unroll
        for (int nt = 0; nt < 2; ++nt) acc[mt][nt] = (f32x4){0.f, 0.f, 0.f, 0.f};

    #pragma unroll
    for (int kk = 0; kk < 4; ++kk) {
        int ko = kk * 32 + quad * 8;
        short8 a[4];
        #pragma unroll
        for (int mt = 0; mt < 4; ++mt)
            a[mt] = *(const short8*)(A2 + (mt * 16 + l15) * 136 + ko);
        #pragma unroll
        for (int nt = 0; nt < 2; ++nt) {
            int n = wave * 32 + nt * 16 + l15;
            short8 b = *(const short8*)(Wot + n * HID + ko);
            #pragma unroll
            for (int mt = 0; mt < 4; ++mt)
                acc[mt][nt] = __builtin_amdgcn_mfma_f32_16x16x32_bf16(a[mt], b, acc[mt][nt], 0, 0, 0);
        }
    }
    __syncthreads();

    #pragma unroll
    for (int nt = 0; nt < 2; ++nt) {
        int col = wave * 32 + nt * 16 + l15;
        float bias = bo[col];
        #pragma unroll
        for (int mt = 0; mt < 4; ++mt) {
            #pragma unroll
            for (int r = 0; r < 4; ++r) {
                int row = mt * 16 + quad * 4 + r;
                int node = n0 + row;
                if (node < NN)
                    out[(size_t)node * HID + col] = acc[mt][nt][r] + bias;
            }
        }
    }
}

extern "C" void kernel_launch(void* const* d_in, const int* in_sizes, int n_in,
                              void* d_out, int out_size, void* d_ws, size_t ws_size,
                              hipStream_t stream) {
    const float* nf  = (const float*)d_in[0];
    const float* pos = (const float*)d_in[1];
    const int*   ei  = (const int*)d_in[2];
    const float* W1  = (const float*)d_in[3];
    const float* b1  = (const float*)d_in[4];
    const float* W2  = (const float*)d_in[5];
    const float* b2  = (const float*)d_in[6];
    const float* Wo  = (const float*)d_in[7];
    const float* bo  = (const float*)d_in[8];
    float* out = (float*)d_out;

    char* ws = (char*)d_ws;
    short* W1aT     = (short*)(ws);                 //     32,768
    short* W1bT     = (short*)(ws + 32768);         //     32,768
    short* W1cT     = (short*)(ws + 65536);         //      8,192
    short* W2t      = (short*)(ws + 73728);         //     32,768
    short* Wot      = (short*)(ws + 106496);        //     32,768
    int*   counts   = (int*)(ws + 139264);          //    200,704
    int*   cur      = (int*)(ws + 339968);          //    200,704
    int*   blockSum = (int*)(ws + 540672);          //      1,024
    int2*  edgeS    = (int2*)(ws + 541696);         //  6,400,000
    short* Sg       = (short*)(ws + 6941696);       // 12,800,000
    short* Dg       = (short*)(ws + 19741696);      // 12,800,000  -> total 32,541,696
    int*   scanEx   = (int*)Sg;   // aliased: dead before perm_sd writes Sg

    (void)hipMemsetAsync(counts, 0, 200704, stream);

    fused_prep<<<3397, 256, 0, stream>>>(ei + NE, counts, W1, W2, Wo,
                                         W1aT, W1bT, W1cT, W2t, Wot, out);
    k_scan1<<<SCAN_B, 256, 0, stream>>>(counts, scanEx, blockSum);
    k_scan23<<<SCAN_B, 256, 0, stream>>>(scanEx, blockSum, cur);
    perm_sd<<<SD_B + 3125, 256, 0, stream>>>(nf, W1aT, W1bT, Sg, Dg,
                                             ei, ei + NE, cur, edgeS);
    edge_kernel<<<NE / 128, 512, 0, stream>>>(Sg, Dg, pos, edgeS,
                                              W1cT, b1, W2t, b2, out);
    out_kernel<<<(NN + 63) / 64, 256, 0, stream>>>(out, counts, Wot, bo);
}

// Round 13
// 325.329 us; speedup vs baseline: 1.2350x; 1.2350x over previous
//
#include <hip/hip_runtime.h>
#include <hip/hip_bf16.h>

#define NN 50000
#define NE 800000
#define HID 128
#define NB 32
#define SCAN_B 196   // 196*256 = 50176 >= NN
#define SD_B 782     // sd tiles: ceil(50000/64)

typedef short short8 __attribute__((ext_vector_type(8)));
typedef float f32x4 __attribute__((ext_vector_type(4)));

static __device__ __forceinline__ short f2bf(float x) {
    union { __hip_bfloat16 h; short s; } r;
    r.h = __float2bfloat16(x);       // HW RNE cvt
    return r.s;
}
static __device__ __forceinline__ float bf2f(unsigned short s) {
    return __uint_as_float(((unsigned int)s) << 16);
}
// packed bf16 add (HW packed add on gfx950)
static __device__ __forceinline__ unsigned int addpack(unsigned int a, unsigned int b) {
    union { unsigned int u; __hip_bfloat162 h; } x, y, r;
    x.u = a; y.u = b;
    r.h = __hadd2(x.h, y.h);
    return r.u;
}

// ---- prep: zero out + dst histogram (blocks < 3125) + weight transposes ----
__global__ void fused_prep(const int* __restrict__ dstI, int* __restrict__ counts,
                           const float* __restrict__ W1, const float* __restrict__ W2,
                           const float* __restrict__ Wo,
                           short* __restrict__ W1aT, short* __restrict__ W1bT,
                           short* __restrict__ W1cT, short* __restrict__ W2t,
                           short* __restrict__ Wot,
                           float* __restrict__ out) {
    int b = blockIdx.x;
    // grid-stride zero of out (all blocks participate; overlaps histogram)
    {
        int gtid = b * 256 + threadIdx.x;
        const int nthr = 3397 * 256;
        float4 z = make_float4(0.f, 0.f, 0.f, 0.f);
        for (int i = gtid; i < NN * HID / 4; i += nthr)
            ((float4*)out)[i] = z;
    }
    if (b < 3125) {
        int e = b * 256 + threadIdx.x;
        atomicAdd(&counts[dstI[e]], 1);
    } else {
        int t = (b - 3125) * 256 + threadIdx.x;   // 0..69631
        if (t < 16384) {
            int n = t >> 7, k = t & 127;
            W1aT[t] = f2bf(W1[k * HID + n]);
        } else if ((t -= 16384) < 16384) {
            int n = t >> 7, k = t & 127;
            W1bT[t] = f2bf(W1[(k + 128) * HID + n]);
        } else if ((t -= 16384) < 4096) {
            int n = t >> 5, k = t & 31;
            W1cT[t] = f2bf(W1[(k + 256) * HID + n]);
        } else if ((t -= 4096) < 16384) {
            int n = t >> 7, k = t & 127;
            W2t[t] = f2bf(W2[k * HID + n]);
        } else if ((t -= 16384) < 16384) {
            int n = t >> 7, k = t & 127;
            Wot[t] = f2bf(Wo[k * HID + n]);
        }
    }
}

// ---- scan stage 1 ----
__global__ void k_scan1(const int* __restrict__ counts, int* __restrict__ scanEx,
                        int* __restrict__ blockSum) {
    __shared__ int s[256];
    int t = threadIdx.x, idx = blockIdx.x * 256 + t;
    int v = counts[idx];   // counts sized 50176, zeroed
    s[t] = v; __syncthreads();
    #pragma unroll
    for (int off = 1; off < 256; off <<= 1) {
        int x = (t >= off) ? s[t - off] : 0;
        __syncthreads();
        s[t] += x;
        __syncthreads();
    }
    scanEx[idx] = s[t] - v;
    if (t == 255) blockSum[blockIdx.x] = s[255];
}

// ---- scan stage 2+3 fused: cur = scanEx + sum(blockSum[0..b)) ----
__global__ void k_scan23(const int* __restrict__ scanEx, const int* __restrict__ blockSum,
                         int* __restrict__ cur) {
    __shared__ int s[256];
    int t = threadIdx.x, b = blockIdx.x;
    s[t] = (t < b) ? blockSum[t] : 0;
    __syncthreads();
    #pragma unroll
    for (int off = 128; off > 0; off >>= 1) {
        if (t < off) s[t] += s[t + off];
        __syncthreads();
    }
    int idx = b * 256 + t;
    cur[idx] = scanEx[idx] + s[0];
}

// ---- fused: sd GEMM (blocks < SD_B) + edge permute (blocks >= SD_B) ----
__launch_bounds__(256, 4)
__global__ void perm_sd(const float* __restrict__ nf,
                        const short* __restrict__ W1aT, const short* __restrict__ W1bT,
                        short* __restrict__ Sg, short* __restrict__ Dg,
                        const int* __restrict__ src, const int* __restrict__ dst,
                        int* __restrict__ cur, int2* __restrict__ edgeS) {
    __shared__ short As[64 * 136];
    const int tid = threadIdx.x;

    if (blockIdx.x >= SD_B) {
        // ---- permute role ----
        int e = (blockIdx.x - SD_B) * 256 + tid;
        int s = src[e];
        int d = dst[e];
        int r = atomicAdd(&cur[d], 1);
        edgeS[r] = make_int2(s, d);
        return;
    }

    // ---- sd role: S = nf@W1a, D = nf@W1b (bf16 out, coalesced via LDS repack) ----
    const int wave = tid >> 6;
    const int lane = tid & 63;
    const int quad = lane >> 4;
    const int l15  = lane & 15;
    const int n0   = blockIdx.x * 64;
    const int row  = tid >> 2, pt = tid & 3;

    {
        int node = min(n0 + row, NN - 1);
        const float4* p = (const float4*)(nf + (size_t)node * HID + pt * 32);
        #pragma unroll
        for (int j = 0; j < 4; ++j) {
            float4 w0 = p[j * 2], w1 = p[j * 2 + 1];
            short8 o;
            o[0] = f2bf(w0.x); o[1] = f2bf(w0.y); o[2] = f2bf(w0.z); o[3] = f2bf(w0.w);
            o[4] = f2bf(w1.x); o[5] = f2bf(w1.y); o[6] = f2bf(w1.z); o[7] = f2bf(w1.w);
            *(short8*)(As + row * 136 + pt * 32 + j * 8) = o;
        }
    }
    __syncthreads();

    f32x4 aS[4][2], aD[4][2];
    #pragma unroll
    for (int mt = 0; mt < 4; ++mt)
        #pragma unroll
        for (int nt = 0; nt < 2; ++nt) {
            aS[mt][nt] = (f32x4){0.f, 0.f, 0.f, 0.f};
            aD[mt][nt] = (f32x4){0.f, 0.f, 0.f, 0.f};
        }

    #pragma unroll
    for (int kk = 0; kk < 4; ++kk) {
        int ko = kk * 32 + quad * 8;
        short8 a[4];
        #pragma unroll
        for (int mt = 0; mt < 4; ++mt)
            a[mt] = *(const short8*)(As + (mt * 16 + l15) * 136 + ko);
        #pragma unroll
        for (int nt = 0; nt < 2; ++nt) {
            int n = wave * 32 + nt * 16 + l15;
            short8 bS = *(const short8*)(W1aT + n * HID + ko);
            short8 bD = *(const short8*)(W1bT + n * HID + ko);
            #pragma unroll
            for (int mt = 0; mt < 4; ++mt) {
                aS[mt][nt] = __builtin_amdgcn_mfma_f32_16x16x32_bf16(a[mt], bS, aS[mt][nt], 0, 0, 0);
                aD[mt][nt] = __builtin_amdgcn_mfma_f32_16x16x32_bf16(a[mt], bD, aD[mt][nt], 0, 0, 0);
            }
        }
    }
    __syncthreads();   // A-frag reads done; reuse As for repack

    // repack S -> coalesced row stores
    #pragma unroll
    for (int nt = 0; nt < 2; ++nt) {
        int col = wave * 32 + nt * 16 + l15;
        #pragma unroll
        for (int mt = 0; mt < 4; ++mt)
            #pragma unroll
            for (int r = 0; r < 4; ++r)
                As[(mt * 16 + quad * 4 + r) * 136 + col] = f2bf(aS[mt][nt][r]);
    }
    __syncthreads();
    if (n0 + row < NN) {
        short8* gp = (short8*)(Sg + (size_t)(n0 + row) * HID + pt * 32);
        #pragma unroll
        for (int j = 0; j < 4; ++j)
            gp[j] = *(const short8*)(As + row * 136 + pt * 32 + j * 8);
    }
    __syncthreads();

    // repack D -> coalesced row stores
    #pragma unroll
    for (int nt = 0; nt < 2; ++nt) {
        int col = wave * 32 + nt * 16 + l15;
        #pragma unroll
        for (int mt = 0; mt < 4; ++mt)
            #pragma unroll
            for (int r = 0; r < 4; ++r)
                As[(mt * 16 + quad * 4 + r) * 136 + col] = f2bf(aD[mt][nt][r]);
    }
    __syncthreads();
    if (n0 + row < NN) {
        short8* gp = (short8*)(Dg + (size_t)(n0 + row) * HID + pt * 32);
        #pragma unroll
        for (int j = 0; j < 4; ++j)
            gp[j] = *(const short8*)(As + row * 136 + pt * 32 + j * 8);
    }
}

// ---- fused edge MLP + tile-merged scatter (edges sorted by dst) ----
// 128 edges/block, 512 threads. Layer1 = rbf@W1c (K=32) + gathered PRE=S[src]+D[dst].
__launch_bounds__(512, 6)
__global__ void edge_kernel(const short* __restrict__ Sg,
                            const short* __restrict__ Dg,
                            const float* __restrict__ pos,
                            const int2* __restrict__ edgeS,
                            const short* __restrict__ W1cT,
                            const float* __restrict__ b1,
                            const short* __restrict__ W2t,
                            const float* __restrict__ b2,
                            float* __restrict__ upd) {
    __shared__ char buf[49152];
    __shared__ int  dn_sh[128];
    short* PRE = (short*)buf;              // [128][136] bf16: S[src]+D[dst]
    short* R   = (short*)(buf + 34816);    // [128][56]  bf16 rbf
    short* Ps  = (short*)buf;              // [128][136] (in-place after PRE consumed)
    float* UfT = (float*)buf;              // [128 cols][68] fp32, one 64-row half

    const int tid  = threadIdx.x;
    const int wave = tid >> 6;
    const int lane = tid & 63;
    const int quad = lane >> 4;
    const int l15  = lane & 15;
    const int mg   = wave >> 2;       // row half: [mg*64, mg*64+64)
    const int nsl  = wave & 3;        // col slice: [nsl*32, nsl*32+32)
    const int e0   = blockIdx.x * 128;

    // ---- stage: PRE = S[src]+D[dst] (packed bf16 HW add), RBF tile, dst ids ----
    {
        int es = tid >> 2, pt = tid & 3;
        int2 sd = edgeS[e0 + es];
        int s = sd.x, d = sd.y;
        const int4* sp = (const int4*)(Sg + (size_t)s * HID + pt * 32);
        const int4* dp = (const int4*)(Dg + (size_t)d * HID + pt * 32);
        int4* op = (int4*)(PRE + es * 136 + pt * 32);
        #pragma unroll
        for (int j = 0; j < 4; ++j) {
            int4 a = sp[j], b = dp[j];
            int4 o;
            o.x = addpack(a.x, b.x);
            o.y = addpack(a.y, b.y);
            o.z = addpack(a.z, b.z);
            o.w = addpack(a.w, b.w);
            op[j] = o;
        }
        if (pt == 0) dn_sh[es] = d;
        float dx = pos[d * 3 + 0] - pos[s * 3 + 0];
        float dy = pos[d * 3 + 1] - pos[s * 3 + 1];
        float dz = pos[d * 3 + 2] - pos[s * 3 + 2];
        float dd = fminf(sqrtf(dx * dx + dy * dy + dz * dz), 5.0f);
        const float step  = 5.0f / 31.0f;
        const float width = 0.5f * (step + 0.01f);
        const float coef  = -0.5f / (width * width);
        short8 r;
        #pragma unroll
        for (int j = 0; j < 8; ++j) {
            float c = step * (float)(pt * 8 + j);
            float t = dd - c;
            r[j] = f2bf(__expf(coef * t * t));
        }
        *(short8*)(R + es * 56 + pt * 8) = r;
    }
    __syncthreads();

    // ---- layer 1: rbf [128x32] @ W1c [32x128], single K-step ----
    f32x4 acc[4][2];
    #pragma unroll
    for (int mt = 0; mt < 4; ++mt)
        #pragma unroll
        for (int nt = 0; nt < 2; ++nt) acc[mt][nt] = (f32x4){0.f, 0.f, 0.f, 0.f};
    {
        int ko = quad * 8;
        short8 a[4];
        #pragma unroll
        for (int mt = 0; mt < 4; ++mt)
            a[mt] = *(const short8*)(R + (mg * 64 + mt * 16 + l15) * 56 + ko);
        #pragma unroll
        for (int nt = 0; nt < 2; ++nt) {
            int n = nsl * 32 + nt * 16 + l15;
            short8 b = *(const short8*)(W1cT + n * NB + ko);
            #pragma unroll
            for (int mt = 0; mt < 4; ++mt)
                acc[mt][nt] = __builtin_amdgcn_mfma_f32_16x16x32_bf16(a[mt], b, acc[mt][nt], 0, 0, 0);
        }
    }

    // ---- + PRE + b1, SiLU -> Ps in place ----
    {
        float b1c[2] = { b1[nsl * 32 + l15], b1[nsl * 32 + 16 + l15] };
        const unsigned short* PREu = (const unsigned short*)PRE;
        #pragma unroll
        for (int nt = 0; nt < 2; ++nt) {
            int col = nsl * 32 + nt * 16 + l15;
            #pragma unroll
            for (int mt = 0; mt < 4; ++mt) {
                #pragma unroll
                for (int r = 0; r < 4; ++r) {
                    int row = mg * 64 + mt * 16 + quad * 4 + r;
                    float pre = bf2f(PREu[row * 136 + col]);
                    float x = acc[mt][nt][r] + pre + b1c[nt];
                    float p = x * __builtin_amdgcn_rcpf(1.0f + __expf(-x));
                    Ps[row * 136 + col] = f2bf(p);
                }
            }
        }
    }
    __syncthreads();

    // ---- layer 2: [128x128] @ [128x128] ----
    f32x4 acc2[4][2];
    #pragma unroll
    for (int mt = 0; mt < 4; ++mt)
        #pragma unroll
        for (int nt = 0; nt < 2; ++nt) acc2[mt][nt] = (f32x4){0.f, 0.f, 0.f, 0.f};

    #pragma unroll
    for (int kk = 0; kk < 4; ++kk) {
        int ko = kk * 32 + quad * 8;
        short8 a[4];
        #pragma unroll
        for (int mt = 0; mt < 4; ++mt)
            a[mt] = *(const short8*)(Ps + (mg * 64 + mt * 16 + l15) * 136 + ko);
        #pragma unroll
        for (int nt = 0; nt < 2; ++nt) {
            int n = nsl * 32 + nt * 16 + l15;
            short8 b = *(const short8*)(W2t + n * HID + ko);
            #pragma unroll
            for (int mt = 0; mt < 4; ++mt)
                acc2[mt][nt] = __builtin_amdgcn_mfma_f32_16x16x32_bf16(a[mt], b, acc2[mt][nt], 0, 0, 0);
        }
    }
    __syncthreads();   // Ps reads done before UfT overwrites

    // ---- two 64-row halves: transposed fp32 buffer + merged scatter ----
    float b2c[2] = { b2[nsl * 32 + l15], b2[nsl * 32 + 16 + l15] };
    #pragma unroll
    for (int h = 0; h < 2; ++h) {
        if (mg == h) {
            #pragma unroll
            for (int nt = 0; nt < 2; ++nt) {
                int col = nsl * 32 + nt * 16 + l15;
                #pragma unroll
                for (int mt = 0; mt < 4; ++mt) {
                    f32x4 v;
                    #pragma unroll
                    for (int r = 0; r < 4; ++r) v[r] = acc2[mt][nt][r] + b2c[nt];
                    *(f32x4*)(UfT + col * 68 + mt * 16 + quad * 4) = v;
                }
            }
        }
        __syncthreads();
        {
            int col = tid & 127;
            int seg = tid >> 7;            // 4 segments x 16 rows
            int rb  = h * 64 + seg * 16;
            const float* cp = UfT + col * 68 + seg * 16;
            f32x4 vv[4];
            #pragma unroll
            for (int j = 0; j < 4; ++j) vv[j] = *(const f32x4*)(cp + j * 4);
            int rnode = dn_sh[rb];
            float run = 0.0f;
            #pragma unroll
            for (int i = 0; i < 16; ++i) {
                int node = dn_sh[rb + i];
                float v = vv[i >> 2][i & 3];
                if (node != rnode) {
                    atomicAdd(upd + (size_t)rnode * HID + col, run);
                    rnode = node;
                    run = v;
                } else {
                    run += v;
                }
            }
            atomicAdd(upd + (size_t)rnode * HID + col, run);
        }
        __syncthreads();
    }
}

// ---- normalize by degree + @Wo + bo (MFMA), in place on d_out ----
__launch_bounds__(256, 4)
__global__ void out_kernel(float* __restrict__ out,
                           const int* __restrict__ counts,
                           const short* __restrict__ Wot,
                           const float* __restrict__ bo) {
    __shared__ short A2[64 * 136];

    const int tid  = threadIdx.x;
    const int wave = tid >> 6;
    const int lane = tid & 63;
    const int quad = lane >> 4;
    const int l15  = lane & 15;
    const int n0   = blockIdx.x * 64;

    {
        int row = tid >> 2, pt = tid & 3;
        int node = n0 + row;
        if (node < NN) {
            float inv = 1.0f / fmaxf((float)counts[node], 1.0f);
            const float4* p = (const float4*)(out + (size_t)node * HID + pt * 32);
            #pragma unroll
            for (int j = 0; j < 4; ++j) {
                float4 w0 = p[j * 2], w1 = p[j * 2 + 1];
                short8 o;
                o[0] = f2bf(w0.x * inv); o[1] = f2bf(w0.y * inv);
                o[2] = f2bf(w0.z * inv); o[3] = f2bf(w0.w * inv);
                o[4] = f2bf(w1.x * inv); o[5] = f2bf(w1.y * inv);
                o[6] = f2bf(w1.z * inv); o[7] = f2bf(w1.w * inv);
                *(short8*)(A2 + row * 136 + pt * 32 + j * 8) = o;
            }
        } else {
            short8 z = (short8){0, 0, 0, 0, 0, 0, 0, 0};
            #pragma unroll
            for (int j = 0; j < 4; ++j)
                *(short8*)(A2 + row * 136 + pt * 32 + j * 8) = z;
        }
    }
    __syncthreads();

    f32x4 acc[4][2];
    #pragma unroll
    for (int mt = 0; mt < 4; ++mt)
        #pragma unroll
        for (int nt = 0; nt < 2; ++nt) acc[mt][nt] = (f32x4){0.f, 0.f, 0.f, 0.f};

    #pragma unroll
    for (int kk = 0; kk < 4; ++kk) {
        int ko = kk * 32 + quad * 8;
        short8 a[4];
        #pragma unroll
        for (int mt = 0; mt < 4; ++mt)
            a[mt] = *(const short8*)(A2 + (mt * 16 + l15) * 136 + ko);
        #pragma unroll
        for (int nt = 0; nt < 2; ++nt) {
            int n = wave * 32 + nt * 16 + l15;
            short8 b = *(const short8*)(Wot + n * HID + ko);
            #pragma unroll
            for (int mt = 0; mt < 4; ++mt)
                acc[mt][nt] = __builtin_amdgcn_mfma_f32_16x16x32_bf16(a[mt], b, acc[mt][nt], 0, 0, 0);
        }
    }
    __syncthreads();

    #pragma unroll
    for (int nt = 0; nt < 2; ++nt) {
        int col = wave * 32 + nt * 16 + l15;
        float bias = bo[col];
        #pragma unroll
        for (int mt = 0; mt < 4; ++mt) {
            #pragma unroll
            for (int r = 0; r < 4; ++r) {
                int row = mt * 16 + quad * 4 + r;
                int node = n0 + row;
                if (node < NN)
                    out[(size_t)node * HID + col] = acc[mt][nt][r] + bias;
            }
        }
    }
}

extern "C" void kernel_launch(void* const* d_in, const int* in_sizes, int n_in,
                              void* d_out, int out_size, void* d_ws, size_t ws_size,
                              hipStream_t stream) {
    const float* nf  = (const float*)d_in[0];
    const float* pos = (const float*)d_in[1];
    const int*   ei  = (const int*)d_in[2];
    const float* W1  = (const float*)d_in[3];
    const float* b1  = (const float*)d_in[4];
    const float* W2  = (const float*)d_in[5];
    const float* b2  = (const float*)d_in[6];
    const float* Wo  = (const float*)d_in[7];
    const float* bo  = (const float*)d_in[8];
    float* out = (float*)d_out;

    char* ws = (char*)d_ws;
    short* W1aT     = (short*)(ws);                 //     32,768
    short* W1bT     = (short*)(ws + 32768);         //     32,768
    short* W1cT     = (short*)(ws + 65536);         //      8,192
    short* W2t      = (short*)(ws + 73728);         //     32,768
    short* Wot      = (short*)(ws + 106496);        //     32,768
    int*   counts   = (int*)(ws + 139264);          //    200,704
    int*   cur      = (int*)(ws + 339968);          //    200,704
    int*   blockSum = (int*)(ws + 540672);          //      1,024
    int2*  edgeS    = (int2*)(ws + 541696);         //  6,400,000
    short* Sg       = (short*)(ws + 6941696);       // 12,800,000
    short* Dg       = (short*)(ws + 19741696);      // 12,800,000  -> total 32,541,696
    int*   scanEx   = (int*)Sg;   // aliased: dead before perm_sd writes Sg

    (void)hipMemsetAsync(counts, 0, 200704, stream);

    fused_prep<<<3397, 256, 0, stream>>>(ei + NE, counts, W1, W2, Wo,
                                         W1aT, W1bT, W1cT, W2t, Wot, out);
    k_scan1<<<SCAN_B, 256, 0, stream>>>(counts, scanEx, blockSum);
    k_scan23<<<SCAN_B, 256, 0, stream>>>(scanEx, blockSum, cur);
    perm_sd<<<SD_B + 3125, 256, 0, stream>>>(nf, W1aT, W1bT, Sg, Dg,
                                             ei, ei + NE, cur, edgeS);
    edge_kernel<<<NE / 128, 512, 0, stream>>>(Sg, Dg, pos, edgeS,
                                              W1cT, b1, W2t, b2, out);
    out_kernel<<<(NN + 63) / 64, 256, 0, stream>>>(out, counts, Wot, bo);
}